// Round 1
// 411.023 us; speedup vs baseline: 1.2245x; 1.2245x over previous
//
#include <hip/hip_runtime.h>
#include <hip/hip_bf16.h>

// Shapes fixed by the reference
#define T_TOK 4096
#define I1    512
#define O1    2049
#define O1P   2176        // padded N1 rows (17*128)
#define K1    4608        // 8*512 spline + 512 silu (= 576 groups, no pad)
#define NG1   576         // K1/8
#define I2    2049
#define O2    512
#define K2    18560       // 8*2049 spline + 2049 silu + 119 pad = 2320 groups
#define NG2   2320        // K2/8
#define HLD   2176        // H row stride (floats), 16B-aligned
#define SPLITS2 8
#define KLEN2 2368        // 37*64; last slice clamps to 31 iters
#define NBY   32          // T_TOK/128, both layers

typedef __attribute__((ext_vector_type(8))) short short8;
typedef __attribute__((ext_vector_type(4))) float floatx4;
typedef __attribute__((address_space(3))) void* lds_ptr_t;
typedef const __attribute__((address_space(1))) void* gmem_ptr_t;

__device__ __forceinline__ unsigned short f2bf(float f) {   // RNE (prep kernels)
  union { __hip_bfloat16 h; unsigned short u; } cv;
  cv.h = __float2bfloat16(f);
  return cv.u;
}
__device__ __forceinline__ unsigned bfr(float f) {          // cheap near-RNE (expand hot path)
  union { float f; unsigned u; } c; c.f = f;
  return (c.u + 0x8000u) >> 16;
}
__device__ __forceinline__ float silu_f(float x) { return x / (1.0f + __expf(-x)); }

// All 8 cubic-basis slots for one group as 8 bf16 in a uint4 (branchless funnel shift).
__device__ __forceinline__ uint4 spline_pack(float h) {
  float u = (h + 2.2f) * 2.5f;
  int ji = (int)u;
  ji = ji < 0 ? 0 : (ji > 10 ? 10 : ji);
  float t = u - (float)ji;
  float it = 1.0f - t, t2 = t * t, t3 = t2 * t;
  float b0 = it * it * it * (1.0f / 6.0f);
  float b1 = (3.0f * t3 - 6.0f * t2 + 4.0f) * (1.0f / 6.0f);
  float b2 = (-3.0f * t3 + 3.0f * t2 + 3.0f * t + 1.0f) * (1.0f / 6.0f);
  float b3 = t3 * (1.0f / 6.0f);
  unsigned pk01 = bfr(b0) | (bfr(b1) << 16);
  unsigned pk23 = bfr(b2) | (bfr(b3) << 16);
  unsigned long long p64 = (unsigned long long)pk01 | ((unsigned long long)pk23 << 32);
  bool inR = (h >= -2.2f) && (h < 2.2f);
  p64 = inR ? p64 : 0ull;
  int sh = (ji - 3) * 16;
  int shr = sh < 0 ? -sh : 0;
  int shl = sh < 0 ? 0 : sh;
  __uint128_t v = ((__uint128_t)(p64 >> shr)) << shl;
  union { __uint128_t q; uint4 u4; } cv;
  cv.q = v;
  return cv.u4;
}

// W1'[o,k]: k<4096 -> spline_w1[o,k>>3,k&7]*scaler1[o,k>>3]; else base_w1; o>=2049 -> 0
__global__ void pack_w1_kernel(const float* __restrict__ bw, const float* __restrict__ sw,
                               const float* __restrict__ sc, unsigned short* __restrict__ W) {
  int k = blockIdx.x * 256 + threadIdx.x;  // grid exact: 18*256 = 4608
  int o = blockIdx.y;                      // < 2176
  float v = 0.0f;
  if (o < O1) {
    if (k < 4096) v = sw[(size_t)o * 4096 + k] * sc[(size_t)o * I1 + (k >> 3)];
    else          v = bw[(size_t)o * I1 + (k - 4096)];
  }
  W[(size_t)o * K1 + k] = f2bf(v);
}

// W2'[o,k]: k<16392 -> spline_w2*scaler2; k<18441 -> base_w2; else 0
__global__ void pack_w2_kernel(const float* __restrict__ bw, const float* __restrict__ sw,
                               const float* __restrict__ sc, unsigned short* __restrict__ W) {
  int k = blockIdx.x * 256 + threadIdx.x;
  if (k >= K2) return;
  int o = blockIdx.y;                      // < 512
  float v = 0.0f;
  if (k < 16392)      v = sw[(size_t)o * 16392 + k] * sc[(size_t)o * I2 + (k >> 3)];
  else if (k < 18441) v = bw[(size_t)o * I2 + (k - 16392)];
  W[(size_t)o * K2 + k] = f2bf(v);
}

// A1[m, g*8..g*8+7]: g<512 -> spline basis of x[m,g]; g>=512 -> silu(x[m, (g-512)*8 + c]).
// Reads coalesced (lane=g), writes coalesced uint4.
__global__ void expand1_kernel(const float* __restrict__ x, unsigned short* __restrict__ A) {
  int g = blockIdx.x * 256 + threadIdx.x;
  if (g >= NG1) return;
  int m = blockIdx.y;
  uint4 val;
  if (g < 512) {
    val = spline_pack(x[(size_t)m * I1 + g]);
  } else {
    const float4* xr = (const float4*)(x + (size_t)m * I1 + (size_t)(g - 512) * 8);
    float4 a = xr[0], b = xr[1];
    union { unsigned short s[8]; uint4 v; } pk;
    pk.s[0] = f2bf(silu_f(a.x)); pk.s[1] = f2bf(silu_f(a.y));
    pk.s[2] = f2bf(silu_f(a.z)); pk.s[3] = f2bf(silu_f(a.w));
    pk.s[4] = f2bf(silu_f(b.x)); pk.s[5] = f2bf(silu_f(b.y));
    pk.s[6] = f2bf(silu_f(b.z)); pk.s[7] = f2bf(silu_f(b.w));
    val = pk.v;
  }
  *(uint4*)(A + (size_t)m * K1 + (size_t)g * 8) = val;
}

// A2[m, g*8..]: g<2049 -> spline basis of H[m,g]; 2049<=g<2306 -> silu(H[m, (g-2049)*8+c])
// (guarded past 2049); g>=2306 -> 0. H has row stride HLD; pad cols never used unguarded.
__global__ void expand2_kernel(const float* __restrict__ H, unsigned short* __restrict__ A) {
  int g = blockIdx.x * 256 + threadIdx.x;
  if (g >= NG2) return;
  int m = blockIdx.y;
  uint4 val;
  if (g < 2049) {
    val = spline_pack(H[(size_t)m * HLD + g]);
  } else if (g < 2306) {
    int c0 = (g - 2049) * 8;
    union { unsigned short s[8]; uint4 v; } pk;
#pragma unroll
    for (int c = 0; c < 8; ++c) {
      int idx = c0 + c;
      float v = (idx < I2) ? silu_f(H[(size_t)m * HLD + idx]) : 0.0f;  // read stays in H pad (in-bounds)
      pk.s[c] = f2bf(v);
    }
    val = pk.v;
  } else {
    val = make_uint4(0u, 0u, 0u, 0u);
  }
  *(uint4*)(A + (size_t)m * K2 + (size_t)g * 8) = val;
}

// Pure bf16 GEMM, C = A(MxK) * B(NxK)^T, both operands row-major bf16 staged via
// global_load_lds w16 with XOR chunk pre-swizzle on the GLOBAL source address
// (linear LDS dest; read side applies the same XOR — both-sides-or-neither rule).
// 1-D grid, XCD-swizzled decode: all bx-siblings (same A window) share Lb%8.
// storeMode 0: plain C[m*ldc+n] store (layer 1). 2: atomicAdd C[m*ldc+n] (layer 2 split-K).
__global__ __launch_bounds__(256, 4)
void gemm_bt_kernel(const unsigned short* __restrict__ Aw, const unsigned short* __restrict__ Bw,
                    float* __restrict__ C, int Ktot, int N, int ldc, int kLen,
                    int nBx, int storeMode)
{
  __shared__ __align__(16) unsigned short As[128 * 64];
  __shared__ __align__(16) unsigned short Bs[128 * 64];

  // Grid decode: Lb = (p&7) + 8*(bx + nBx*(p>>3)), p = by + NBY*bz
  const int Lb = blockIdx.x;
  const int m8 = Lb & 7;
  const int r  = Lb >> 3;
  const int bx = r % nBx;
  const int p  = m8 + ((r / nBx) << 3);
  const int by = p & (NBY - 1);
  const int bz = p >> 5;                   // NBY = 32

  const int tid = threadIdx.x;
  const int ks = bz * kLen;
  int ke = ks + kLen; if (ke > Ktot) ke = Ktot;

  const int w = tid >> 6, L = tid & 63, q = L >> 4, ln = L & 15;
  const int wm = (w & 1) << 6, wn = (w >> 1) << 6;

  floatx4 zf = {0.f, 0.f, 0.f, 0.f};
  floatx4 acc[4][4];
#pragma unroll
  for (int mt = 0; mt < 4; ++mt)
#pragma unroll
    for (int nt = 0; nt < 4; ++nt)
      acc[mt][nt] = zf;

  // Staging: 4 chunks/thread/operand, lane-contiguous LDS dest (wave-uniform base + lane*16)
  const unsigned short* ga[4];
  const unsigned short* gb[4];
  int ldsOff[4];
#pragma unroll
  for (int r4 = 0; r4 < 4; ++r4) {
    int e = r4 * 256 + tid;
    int br = e >> 3;
    int cg = (e & 7) ^ (br & 7);
    ga[r4] = Aw + ((long)by * 128 + br) * (long)Ktot + ks + cg * 8;
    gb[r4] = Bw + ((long)bx * 128 + br) * (long)Ktot + ks + cg * 8;
    ldsOff[r4] = e * 8;
  }

  for (int kc = ks; kc < ke; kc += 64) {
    __syncthreads();                        // prior MFMA done reading LDS
#pragma unroll
    for (int r4 = 0; r4 < 4; ++r4) {
      __builtin_amdgcn_global_load_lds((gmem_ptr_t)ga[r4], (lds_ptr_t)&As[ldsOff[r4]], 16, 0, 0);
      ga[r4] += 64;
      __builtin_amdgcn_global_load_lds((gmem_ptr_t)gb[r4], (lds_ptr_t)&Bs[ldsOff[r4]], 16, 0, 0);
      gb[r4] += 64;
    }
    __syncthreads();                        // DMA drained (vmcnt(0) at barrier)

#pragma unroll
    for (int s = 0; s < 2; ++s) {
      short8 af[4], bf[4];
#pragma unroll
      for (int mt = 0; mt < 4; ++mt) {
        int rr = wm + mt * 16 + ln;
        int cl = ((s << 2) | q) ^ (rr & 7);
        af[mt] = *(const short8*)&As[rr * 64 + cl * 8];
      }
#pragma unroll
      for (int nt = 0; nt < 4; ++nt) {
        int rr = wn + nt * 16 + ln;
        int cl = ((s << 2) | q) ^ (rr & 7);
        bf[nt] = *(const short8*)&Bs[rr * 64 + cl * 8];
      }
#pragma unroll
      for (int mt = 0; mt < 4; ++mt)
#pragma unroll
        for (int nt = 0; nt < 4; ++nt)
          acc[mt][nt] = __builtin_amdgcn_mfma_f32_16x16x32_bf16(af[mt], bf[nt], acc[mt][nt], 0, 0, 0);
    }
  }

  // Epilogue. D layout: col = lane&15 (n), row = q*4+reg (m)  [m89-verified]
  if (storeMode == 0) {                     // plain row-major store (layer 1 -> H)
#pragma unroll
    for (int mt = 0; mt < 4; ++mt) {
#pragma unroll
      for (int nt = 0; nt < 4; ++nt) {
        int n = bx * 128 + wn + nt * 16 + ln;
        if (n < N) {
          int m0 = by * 128 + wm + mt * 16 + q * 4;
#pragma unroll
          for (int rg = 0; rg < 4; ++rg)
            C[(size_t)(m0 + rg) * ldc + n] = acc[mt][nt][rg];
        }
      }
    }
  } else {                                  // atomic accumulate (layer 2, split-K)
#pragma unroll
    for (int mt = 0; mt < 4; ++mt) {
#pragma unroll
      for (int nt = 0; nt < 4; ++nt) {
        int n = bx * 128 + wn + nt * 16 + ln;
        if (n < N) {
          int m0 = by * 128 + wm + mt * 16 + q * 4;
#pragma unroll
          for (int rg = 0; rg < 4; ++rg)
            atomicAdd(&C[(size_t)(m0 + rg) * ldc + n], acc[mt][nt][rg]);
        }
      }
    }
  }
}

extern "C" void kernel_launch(void* const* d_in, const int* in_sizes, int n_in,
                              void* d_out, int out_size, void* d_ws, size_t ws_size,
                              hipStream_t stream) {
  const float* x   = (const float*)d_in[0];
  const float* bw1 = (const float*)d_in[1];
  const float* sw1 = (const float*)d_in[2];
  const float* sc1 = (const float*)d_in[3];
  const float* bw2 = (const float*)d_in[4];
  const float* sw2 = (const float*)d_in[5];
  const float* sc2 = (const float*)d_in[6];
  float* out = (float*)d_out;

  // Workspace: H (35.7MB) | W2 (19.0MB) | A2 (152.0MB, overlaid by A1(37.7)+W1(20.1))
  // A1/W1 die at gemm1; expand2 overwrites their region (stream-ordered). Total ~207MB.
  float* H = (float*)d_ws;                                         // 4096*2176 fp32
  unsigned short* W2 = (unsigned short*)(H + (size_t)T_TOK * HLD); // 512*18560 bf16
  unsigned short* A2 = W2 + (size_t)O2 * K2;                       // 4096*18560 bf16
  unsigned short* A1 = A2;                                         // alias (first 37.7MB)
  unsigned short* W1 = A1 + (size_t)T_TOK * K1;                    // next 20.1MB

  hipMemsetAsync(d_out, 0, (size_t)out_size * sizeof(float), stream);

  pack_w1_kernel<<<dim3(K1 / 256, O1P), 256, 0, stream>>>(bw1, sw1, sc1, W1);
  pack_w2_kernel<<<dim3((K2 + 255) / 256, O2), 256, 0, stream>>>(bw2, sw2, sc2, W2);
  expand1_kernel<<<dim3((NG1 + 255) / 256, T_TOK), 256, 0, stream>>>(x, A1);

  // Layer 1: H = A1 @ W1'^T. M=4096, N=2049 (rows pad 2176), K=4608. 544 blocks.
  gemm_bt_kernel<<<(O1P / 128) * NBY, 256, 0, stream>>>(
      A1, W1, H, K1, O1, HLD, K1, O1P / 128, 0);

  expand2_kernel<<<dim3((NG2 + 255) / 256, T_TOK), 256, 0, stream>>>(H, A2);

  // Layer 2: out += A2 @ W2'^T. M=4096, N=512, K=18560, split-K=8 -> 1024 blocks.
  gemm_bt_kernel<<<(O2 / 128) * NBY * SPLITS2, 256, 0, stream>>>(
      A2, W2, out, K2, O2, O2, KLEN2, O2 / 128, 2);
}